// Round 5
// baseline (1250.066 us; speedup 1.0000x reference)
//
#include <hip/hip_runtime.h>
#include <hip/hip_fp16.h>

#define IN_DIM 512
#define OUT_DIM 16
#define KC 32
#define TILE_ROWS 256
#define BSH 6                     // log2(nodes per bucket)
#define BNODES 64                 // nodes per bucket
#define SRC_BITS 17               // node id fits in 17 bits (n <= 131072)

// ---------------------------------------------------------------------------
// hp(fp16) = dinv ⊙ (x @ W) : fp32 vector GEMM, x via LDS 256x32 tiles.
// ---------------------------------------------------------------------------
__global__ __launch_bounds__(256) void gemm_xw(const float* __restrict__ x,
                                               const float* __restrict__ W,
                                               const float* __restrict__ dinv,
                                               __half* __restrict__ hp, int n) {
    __shared__ float xs[TILE_ROWS * (KC + 1)];
    const int tid = threadIdx.x;
    const int rbase = blockIdx.x * TILE_ROWS;
    const int myrow = rbase + tid;

    float acc[OUT_DIM];
#pragma unroll
    for (int j = 0; j < OUT_DIM; ++j) acc[j] = 0.f;

    for (int kc = 0; kc < IN_DIM; kc += KC) {
        __syncthreads();
#pragma unroll
        for (int i = 0; i < 8; ++i) {
            const int v = tid + 256 * i;
            const int r = v >> 3;
            const int c = (v & 7) << 2;
            if (rbase + r < n) {
                const float4 f = *(const float4*)(x + (size_t)(rbase + r) * IN_DIM + kc + c);
                float* d = xs + r * (KC + 1) + c;
                d[0] = f.x; d[1] = f.y; d[2] = f.z; d[3] = f.w;
            }
        }
        __syncthreads();

        const float* xrow = xs + tid * (KC + 1);
#pragma unroll 4
        for (int k = 0; k < KC; ++k) {
            const float xv = xrow[k];
            const float* wr = W + (size_t)(kc + k) * OUT_DIM;   // uniform -> s_load
            const float4 w0 = *(const float4*)(wr + 0);
            const float4 w1 = *(const float4*)(wr + 4);
            const float4 w2 = *(const float4*)(wr + 8);
            const float4 w3 = *(const float4*)(wr + 12);
            acc[0]  += xv * w0.x; acc[1]  += xv * w0.y; acc[2]  += xv * w0.z; acc[3]  += xv * w0.w;
            acc[4]  += xv * w1.x; acc[5]  += xv * w1.y; acc[6]  += xv * w1.z; acc[7]  += xv * w1.w;
            acc[8]  += xv * w2.x; acc[9]  += xv * w2.y; acc[10] += xv * w2.z; acc[11] += xv * w2.w;
            acc[12] += xv * w3.x; acc[13] += xv * w3.y; acc[14] += xv * w3.z; acc[15] += xv * w3.w;
        }
    }

    if (myrow < n) {
        const float s = dinv[myrow];
        __half2* op = (__half2*)(hp + (size_t)myrow * OUT_DIM);
#pragma unroll
        for (int j = 0; j < 8; ++j)
            op[j] = __floats2half2_rn(s * acc[2 * j], s * acc[2 * j + 1]);
    }
}

// in-degree histogram over targets
__global__ void hist_dst(const int* __restrict__ dst, int* __restrict__ hist, int E) {
    const int e = blockIdx.x * 256 + threadIdx.x;
    if (e < E) atomicAdd(&hist[dst[e]], 1);
}

// dinv[i] = rsqrt(deg+1); bucket_cnt[b] = sum of hist over b's 64 nodes
__global__ void dinv_bucket(const int* __restrict__ hist, float* __restrict__ dinv,
                            int* __restrict__ bucket_cnt, int n, int nb) {
    __shared__ int s[256];
    const int tid = threadIdx.x;
    const int i = blockIdx.x * 256 + tid;
    const int h = (i < n) ? hist[i] : 0;
    if (i < n) dinv[i] = rsqrtf((float)(h + 1));
    s[tid] = h;
    __syncthreads();
#pragma unroll
    for (int off = 32; off > 0; off >>= 1) {
        if ((tid & 63) < off) s[tid] += s[tid + off];
        __syncthreads();
    }
    if ((tid & 63) == 0) {
        const int b = blockIdx.x * 4 + (tid >> 6);
        if (b < nb) bucket_cnt[b] = s[tid];
    }
}

// single block: exclusive scan of bucket_cnt -> bucket_off, cursor
__global__ void scan_buckets(const int* __restrict__ bucket_cnt, int* __restrict__ bucket_off,
                             int* __restrict__ cursor, int nb, int E) {
    __shared__ int s[256];
    const int tid = threadIdx.x;
    const int chunk = (nb + 255) / 256;
    const int beg = tid * chunk;
    int tot = 0;
    for (int c = 0; c < chunk; ++c) {
        const int b = beg + c;
        if (b < nb) tot += bucket_cnt[b];
    }
    s[tid] = tot;
    __syncthreads();
    const int v = tot;
    for (int off = 1; off < 256; off <<= 1) {
        const int t = (tid >= off) ? s[tid - off] : 0;
        __syncthreads();
        s[tid] += t;
        __syncthreads();
    }
    int run = s[tid] - v;   // exclusive prefix of this thread's chunk
    for (int c = 0; c < chunk; ++c) {
        const int b = beg + c;
        if (b < nb) {
            bucket_off[b] = run;
            cursor[b] = run;
            run += bucket_cnt[b];
        }
    }
    if (tid == 0) bucket_off[nb] = E;
}

// bin edges by dst bucket; payload = src | (dst&63)<<17 (4 B)
__global__ void edge_bin(const int* __restrict__ ei, int* __restrict__ cursor,
                         int* __restrict__ binned, int E) {
    const int e = blockIdx.x * 256 + threadIdx.x;
    if (e < E) {
        const int src = ei[e];
        const int dst = ei[(size_t)E + e];
        const int p = atomicAdd(&cursor[dst >> BSH], 1);
        binned[p] = src | ((dst & (BNODES - 1)) << SRC_BITS);
    }
}

// one block per bucket: LDS fp32 accumulation, fused self-term + bias + store
__global__ __launch_bounds__(256) void aggregate(const int* __restrict__ bucket_off,
                                                 const int* __restrict__ binned,
                                                 const __half* __restrict__ hp,
                                                 const float* __restrict__ dinv,
                                                 const float* __restrict__ b,
                                                 float* __restrict__ out, int n) {
    __shared__ float acc[BNODES * OUT_DIM];   // 4 KB
    const int tid = threadIdx.x;
    for (int i = tid; i < BNODES * OUT_DIM; i += 256) acc[i] = 0.f;
    __syncthreads();

    const int beg = bucket_off[blockIdx.x];
    const int end = bucket_off[blockIdx.x + 1];
    const int j = tid & 15;

    for (int e = beg + (tid >> 4); e < end; e += 16) {
        const int w = binned[e];                       // same addr for 16 lanes -> broadcast
        const int src = w & ((1 << SRC_BITS) - 1);
        const int d6 = w >> SRC_BITS;
        const float v = __half2float(hp[(size_t)src * OUT_DIM + j]);
        atomicAdd(&acc[d6 * OUT_DIM + j], v);
    }
    __syncthreads();

    const int base = blockIdx.x * BNODES;
    for (int i = tid; i < BNODES * OUT_DIM; i += 256) {
        const int node = base + (i >> 4);
        if (node < n) {
            const int jj = i & 15;
            out[(size_t)node * OUT_DIM + jj] =
                dinv[node] * (acc[i] + __half2float(hp[(size_t)node * OUT_DIM + jj])) + b[jj];
        }
    }
}

// ---------------- fallback (R4-style, fp16 hp) ------------------------------

__global__ __launch_bounds__(256) void scatter_f16(const int* __restrict__ ei,
                                                   const __half* __restrict__ hp,
                                                   __half2* __restrict__ acc, int E) {
    const long long gid = (long long)blockIdx.x * 256 + threadIdx.x;
    const int e = (int)(gid >> 3);
    if (e >= E) return;
    const int j2 = (int)(gid & 7);
    const int src = ei[e];
    const int dst = ei[(size_t)E + e];
    const __half2 v = ((const __half2*)(hp + (size_t)src * OUT_DIM))[j2];
    unsafeAtomicAdd(&acc[(size_t)dst * 8 + j2], v);
}
__global__ void finalize(const __half* __restrict__ acc, const __half* __restrict__ hp,
                         const float* __restrict__ dinv, const float* __restrict__ b,
                         float* __restrict__ out, int n) {
    const int gid = blockIdx.x * 256 + threadIdx.x;
    if (gid >= n * OUT_DIM) return;
    const int i = gid >> 4;
    const int j = gid & 15;
    out[gid] = dinv[i] * (__half2float(acc[gid]) + __half2float(hp[gid])) + b[j];
}

// ---------------------------------------------------------------------------

extern "C" void kernel_launch(void* const* d_in, const int* in_sizes, int n_in,
                              void* d_out, int out_size, void* d_ws, size_t ws_size,
                              hipStream_t stream) {
    const float* x  = (const float*)d_in[0];
    const int*   ei = (const int*)d_in[1];   // int inputs delivered as int32
    const float* W  = (const float*)d_in[2];
    const float* b  = (const float*)d_in[3];
    float* out = (float*)d_out;

    const int n = in_sizes[0] / IN_DIM;   // 100000
    const int E = in_sizes[1] / 2;        // 3200000
    const int nb = (n + BNODES - 1) / BNODES;   // 1563 buckets

    // ws layout: hp [n*16 f16] | hist [n i32] | dinv [n f32] |
    //            bucket_cnt [nb] | bucket_off [nb+1] | cursor [nb] | binned [E i32]
    __half* hp        = (__half*)d_ws;
    int*    hist      = (int*)(hp + (size_t)n * OUT_DIM);
    float*  dinv      = (float*)(hist + n);
    int*    bcnt      = (int*)(dinv + n);
    int*    boff      = bcnt + nb;
    int*    cursor    = boff + nb + 1;
    int*    binned    = cursor + nb;
    const size_t need = (size_t)n * OUT_DIM * 2 + (size_t)(2 * n) * 4 +
                        (size_t)(3 * nb + 1) * 4 + (size_t)E * 4;

    if (ws_size >= need && n <= (1 << SRC_BITS)) {
        hipMemsetAsync(hist, 0, (size_t)n * sizeof(int), stream);
        hist_dst<<<(E + 255) / 256, 256, 0, stream>>>(ei + E, hist, E);
        dinv_bucket<<<(n + 255) / 256, 256, 0, stream>>>(hist, dinv, bcnt, n, nb);
        scan_buckets<<<1, 256, 0, stream>>>(bcnt, boff, cursor, nb, E);
        edge_bin<<<(E + 255) / 256, 256, 0, stream>>>(ei, cursor, binned, E);
        gemm_xw<<<(n + TILE_ROWS - 1) / TILE_ROWS, 256, 0, stream>>>(x, W, dinv, hp, n);
        aggregate<<<nb, 256, 0, stream>>>(boff, binned, hp, dinv, b, out, n);
    } else {
        // fallback: direct packed-fp16 atomic scatter (R4 structure)
        __half* acc = (__half*)(dinv + n);
        hipMemsetAsync(hist, 0, (size_t)n * sizeof(int), stream);
        hipMemsetAsync(acc, 0, (size_t)n * OUT_DIM * sizeof(__half), stream);
        hist_dst<<<(E + 255) / 256, 256, 0, stream>>>(ei + E, hist, E);
        dinv_bucket<<<(n + 255) / 256, 256, 0, stream>>>(hist, dinv, bcnt, n, 0);
        gemm_xw<<<(n + TILE_ROWS - 1) / TILE_ROWS, 256, 0, stream>>>(x, W, dinv, hp, n);
        const long long st = (long long)E * 8;
        scatter_f16<<<(int)((st + 255) / 256), 256, 0, stream>>>(ei, hp, (__half2*)acc, E);
        finalize<<<(n * OUT_DIM + 255) / 256, 256, 0, stream>>>(acc, hp, dinv, b, out, n);
    }
}

// Round 6
// 641.370 us; speedup vs baseline: 1.9491x; 1.9491x over previous
//
#include <hip/hip_runtime.h>
#include <hip/hip_fp16.h>

#define IN_DIM 512
#define OUT_DIM 16
#define KC 32
#define TILE_ROWS 256

// ---------------------------------------------------------------------------
// hp(fp16) = rsqrt(deg) ⊙ (x @ W) : fp32 vector GEMM, x via LDS 256x32 tiles
// (pad +1 -> 2-way bank alias, free). W loads wave-uniform -> scalar path.
// ---------------------------------------------------------------------------
__global__ __launch_bounds__(256) void gemm_xw(const float* __restrict__ x,
                                               const float* __restrict__ W,
                                               const int* __restrict__ hist,
                                               __half* __restrict__ hp, int n) {
    __shared__ float xs[TILE_ROWS * (KC + 1)];
    const int tid = threadIdx.x;
    const int rbase = blockIdx.x * TILE_ROWS;
    const int myrow = rbase + tid;

    float acc[OUT_DIM];
#pragma unroll
    for (int j = 0; j < OUT_DIM; ++j) acc[j] = 0.f;

    for (int kc = 0; kc < IN_DIM; kc += KC) {
        __syncthreads();
#pragma unroll
        for (int i = 0; i < 8; ++i) {
            const int v = tid + 256 * i;
            const int r = v >> 3;
            const int c = (v & 7) << 2;
            if (rbase + r < n) {
                const float4 f = *(const float4*)(x + (size_t)(rbase + r) * IN_DIM + kc + c);
                float* d = xs + r * (KC + 1) + c;
                d[0] = f.x; d[1] = f.y; d[2] = f.z; d[3] = f.w;
            }
        }
        __syncthreads();

        const float* xrow = xs + tid * (KC + 1);
#pragma unroll 4
        for (int k = 0; k < KC; ++k) {
            const float xv = xrow[k];
            const float* wr = W + (size_t)(kc + k) * OUT_DIM;   // uniform -> s_load
            const float4 w0 = *(const float4*)(wr + 0);
            const float4 w1 = *(const float4*)(wr + 4);
            const float4 w2 = *(const float4*)(wr + 8);
            const float4 w3 = *(const float4*)(wr + 12);
            acc[0]  += xv * w0.x; acc[1]  += xv * w0.y; acc[2]  += xv * w0.z; acc[3]  += xv * w0.w;
            acc[4]  += xv * w1.x; acc[5]  += xv * w1.y; acc[6]  += xv * w1.z; acc[7]  += xv * w1.w;
            acc[8]  += xv * w2.x; acc[9]  += xv * w2.y; acc[10] += xv * w2.z; acc[11] += xv * w2.w;
            acc[12] += xv * w3.x; acc[13] += xv * w3.y; acc[14] += xv * w3.z; acc[15] += xv * w3.w;
        }
    }

    if (myrow < n) {
        const float s = rsqrtf((float)(hist[myrow] + 1));
        __half2* op = (__half2*)(hp + (size_t)myrow * OUT_DIM);
#pragma unroll
        for (int j = 0; j < 8; ++j)
            op[j] = __floats2half2_rn(s * acc[2 * j], s * acc[2 * j + 1]);
    }
}

// in-degree histogram over targets (400 KB, L2-resident int atomics)
__global__ void hist_dst(const int* __restrict__ dst, int* __restrict__ hist, int E) {
    const int e = blockIdx.x * 256 + threadIdx.x;
    if (e < E) atomicAdd(&hist[dst[e]], 1);
}

// per edge (src->dst): acc16[dst][:] += hp[src][:]
// 8 lanes/edge (32B coalesced gather, 4B packed-fp16 atomic per lane),
// 4 edges per lane-group -> 4 independent gathers in flight (latency hiding).
__global__ __launch_bounds__(256) void scatter_f16(const int* __restrict__ ei,
                                                   const __half* __restrict__ hp,
                                                   __half2* __restrict__ acc, int E) {
    const long long gid = (long long)blockIdx.x * 256 + threadIdx.x;
    const int g = (int)(gid >> 3);        // lane group -> 4 edges
    const int j2 = (int)(gid & 7);
    const int e0 = g * 4;
    if (e0 >= E) return;

    int src[4], dst[4];
#pragma unroll
    for (int u = 0; u < 4; ++u) {
        const int e = e0 + u;
        src[u] = (e < E) ? ei[e] : -1;
        dst[u] = (e < E) ? ei[(size_t)E + e] : -1;
    }
    __half2 v[4];
#pragma unroll
    for (int u = 0; u < 4; ++u)
        if (src[u] >= 0) v[u] = ((const __half2*)(hp + (size_t)src[u] * OUT_DIM))[j2];
#pragma unroll
    for (int u = 0; u < 4; ++u)
        if (dst[u] >= 0) unsafeAtomicAdd(&acc[(size_t)dst[u] * 8 + j2], v[u]);
}

// out[d][j] = rsqrt(deg[d]) * (acc16[d][j] + hp[d][j]) + b[j]
__global__ void finalize(const __half* __restrict__ acc, const __half* __restrict__ hp,
                         const int* __restrict__ hist, const float* __restrict__ b,
                         float* __restrict__ out, int n) {
    const int gid = blockIdx.x * 256 + threadIdx.x;
    if (gid >= n * OUT_DIM) return;
    const int i = gid >> 4;
    const int j = gid & 15;
    const float di = rsqrtf((float)(hist[i] + 1));
    out[gid] = di * (__half2float(acc[gid]) + __half2float(hp[gid])) + b[j];
}

// ---------------------------------------------------------------------------

extern "C" void kernel_launch(void* const* d_in, const int* in_sizes, int n_in,
                              void* d_out, int out_size, void* d_ws, size_t ws_size,
                              hipStream_t stream) {
    const float* x  = (const float*)d_in[0];
    const int*   ei = (const int*)d_in[1];   // int inputs delivered as int32
    const float* W  = (const float*)d_in[2];
    const float* b  = (const float*)d_in[3];
    float* out = (float*)d_out;

    const int n = in_sizes[0] / IN_DIM;   // 100000
    const int E = in_sizes[1] / 2;        // 3200000

    // ws layout: hp [n*16 f16] | hist [n i32] | acc16 [n*16 f16]   (~7.2 MB)
    __half* hp   = (__half*)d_ws;
    int*    hist = (int*)(hp + (size_t)n * OUT_DIM);
    __half* acc  = (__half*)(hist + n);

    hipMemsetAsync(hist, 0, (size_t)n * sizeof(int), stream);
    hipMemsetAsync(acc, 0, (size_t)n * OUT_DIM * sizeof(__half), stream);

    hist_dst<<<(E + 255) / 256, 256, 0, stream>>>(ei + E, hist, E);

    gemm_xw<<<(n + TILE_ROWS - 1) / TILE_ROWS, 256, 0, stream>>>(x, W, hist, hp, n);

    const long long st = ((long long)(E + 3) / 4) * 8;   // 8 lanes per 4 edges
    scatter_f16<<<(int)((st + 255) / 256), 256, 0, stream>>>(ei, hp, (__half2*)acc, E);

    finalize<<<(n * OUT_DIM + 255) / 256, 256, 0, stream>>>(acc, hp, hist, b, out, n);
}